// Round 3
// baseline (953.562 us; speedup 1.0000x reference)
//
#include <hip/hip_runtime.h>

#define FS 11
#define HFS 5

constexpr int Bn = 8, Cn = 19, Hn = 512, Wn = 512;
constexpr int HWn = Hn * Wn;            // 262144
constexpr int CHWn = Cn * HWn;          // 4980736
constexpr int TOTn = Bn * CHWn;         // 39845888

constexpr int TH = 32, TW = 64;
constexpr int HR  = TH + 10;            // 42 halo rows (h0-5 .. h0+36)
constexpr int NT  = HR * 8;             // 336 convW tasks (row r, 8-col group g)
constexpr int WSS = 68;                 // ws row stride; 68%32=4 -> staggered bank starts

// wave-uniform float -> SGPR (b is uniform per block)
__device__ __forceinline__ float rfl(float x) {
    return __uint_as_float(__builtin_amdgcn_readfirstlane(__float_as_uint(x)));
}

// taps[b][dim][j]: dim0 = kh (H-direction), dim1 = kw (W-direction, scaled by weight)
__global__ void k_taps(const float* __restrict__ spacing,
                       const float* __restrict__ inv_theta,
                       const float* __restrict__ wgt,
                       float* __restrict__ taps) {
    int t = threadIdx.x;
    if (t < Bn * 2 * FS) {
        int j = t % FS;
        int dim = (t / FS) & 1;
        int b = t / (2 * FS);
        float d = spacing[b * 2 + dim] * (float)(j - HFS);
        float a = d * inv_theta[dim];
        float k = __expf(-0.5f * a * a);
        if (j == HFS) k = 0.0f;          // message passing excludes self
        if (dim == 1) k *= wgt[0];       // fold smoothness_weight into kw
        taps[t] = k;
    }
}

// rinv for the 18 used cols of one task window (sum of exp over channels, direct-global)
#define PASS1(XO, VM, RI) do {                                                   \
    float s_[18];                                                                \
    _Pragma("unroll") for (int i = 0; i < 18; ++i) s_[i] = 0.f;                  \
    for (int c_ = Cn - 1; c_ >= 0; --c_) {                                       \
        float4 p_[6];                                                            \
        _Pragma("unroll") for (int m = 0; m < 6; ++m) {                          \
            float4 v_ = {0.f, 0.f, 0.f, 0.f};                                    \
            if (((VM) >> m) & 1) v_ = *(const float4*)(xb + c_ * HWn + (XO) + 4 * m); \
            p_[m] = v_; }                                                        \
        const float* pf_ = (const float*)p_;                                     \
        _Pragma("unroll") for (int i = 0; i < 18; ++i) s_[i] += __expf(pf_[i + 3]); \
    }                                                                            \
    _Pragma("unroll") for (int i = 0; i < 18; ++i) RI[i] = 1.f / s_[i];          \
} while (0)

// convW for one task: q = exp(x)*rinv on the fly, write 8 outputs to ws[BUF]
#define A_STAGE(PX, RI, VM, LO, BUF) do {                                        \
    const float* pf_ = (const float*)(PX);                                       \
    float q_[18];                                                                \
    _Pragma("unroll") for (int i = 0; i < 18; ++i) {                             \
        float e_ = __expf(pf_[i + 3]) * RI[i];                                   \
        q_[i] = (((VM) >> ((i + 3) >> 2)) & 1) ? e_ : 0.f; }                     \
    float o_[8];                                                                 \
    _Pragma("unroll") for (int k_ = 0; k_ < 8; ++k_) {                           \
        float a_ = 0.f;                                                          \
        _Pragma("unroll") for (int j_ = 0; j_ < FS; ++j_) {                      \
            if (j_ == HFS) continue;                                             \
            a_ = fmaf(kw[j_], q_[k_ + j_], a_); }                                \
        o_[k_] = a_; }                                                           \
    float4 oa_ = {o_[0], o_[1], o_[2], o_[3]};                                   \
    float4 ob_ = {o_[4], o_[5], o_[6], o_[7]};                                   \
    *(float4*)&ws[BUF][(LO)]     = oa_;                                          \
    *(float4*)&ws[BUF][(LO) + 4] = ob_;                                          \
} while (0)

// convH + x0-add for channel CC (reads ws[CC&1]); XA/XB prefetched last iteration
#define B_PHASE(CC, XA, XB) do {                                                 \
    const float* wb_ = ws[(CC) & 1];                                             \
    float4 o0_ = {0.f, 0.f, 0.f, 0.f}, o1_ = {0.f, 0.f, 0.f, 0.f};               \
    _Pragma("unroll") for (int j_ = 0; j_ < 12; ++j_) {                          \
        float4 v_ = *(const float4*)&wb_[bws + j_ * WSS];                        \
        if (j_ < 11 && j_ != HFS) { float kj_ = kh[j_];                          \
            o0_.x = fmaf(kj_, v_.x, o0_.x); o0_.y = fmaf(kj_, v_.y, o0_.y);      \
            o0_.z = fmaf(kj_, v_.z, o0_.z); o0_.w = fmaf(kj_, v_.w, o0_.w); }    \
        if (j_ >= 1 && j_ != HFS + 1) { float kj_ = kh[j_ - 1];                  \
            o1_.x = fmaf(kj_, v_.x, o1_.x); o1_.y = fmaf(kj_, v_.y, o1_.y);      \
            o1_.z = fmaf(kj_, v_.z, o1_.z); o1_.w = fmaf(kj_, v_.w, o1_.w); } }  \
    int gi_ = (b * Cn + (CC)) * HWn + pix;                                       \
    float4 ra_ = {(XA).x + o0_.x, (XA).y + o0_.y, (XA).z + o0_.z, (XA).w + o0_.w}; \
    float4 rb_ = {(XB).x + o1_.x, (XB).y + o1_.y, (XB).z + o1_.z, (XB).w + o1_.w}; \
    *(float4*)(xout + gi_)      = ra_;                                           \
    *(float4*)(xout + gi_ + Wn) = rb_;                                           \
} while (0)

// One block = one (b, 32x64 tile), all 19 channels. Single barrier per channel:
// iteration c = [issue A(c) global loads | B(c-1) from ws[(c-1)&1] | prefetch x0(c) |
//                A(c) -> ws[c&1]] barrier.  rinv lives in registers (per-task window).
__global__ __launch_bounds__(256, 4) void k_fused(const float* __restrict__ xin,
                                                  const float* __restrict__ x0,
                                                  float* __restrict__ xout,
                                                  const float* __restrict__ taps) {
    __shared__ float ws[2][HR * WSS];    // 22848 B double-buffered convW intermediate

    const int tid = threadIdx.x;
    // XCD-chunked swizzle: 1024 blocks = 8 XCDs x 128 contiguous tiles (one image each)
    const int id = blockIdx.x;
    const int fl = (id & 7) * 128 + (id >> 3);
    const int b  = fl >> 7;
    const int ty = (fl & 127) >> 3, tx = fl & 7;
    const int h0 = ty * TH, w0 = tx * TW;

    const float* tp = taps + b * (2 * FS);
    float kh[FS], kw[FS];
#pragma unroll
    for (int j = 0; j < FS; j++) { kh[j] = rfl(tp[j]); kw[j] = rfl(tp[FS + j]); }

    const float* xb = xin + b * CHWn;

    // ---- task geometry: task1 = tid, task2 = tid+256 (threads 0..79) ----
    int xo1 = 0, lo1 = 0, vm1 = 0, xo2 = 0, lo2 = 0, vm2 = 0;
    {
        int r = tid >> 3, g = tid & 7;
        int hh = h0 - 5 + r, wc = w0 - 8 + 8 * g;
        xo1 = hh * Wn + wc; lo1 = r * WSS + 8 * g;
        if (hh >= 0 && hh < Hn) {
#pragma unroll
            for (int m = 0; m < 6; ++m)
                if (wc + 4 * m >= 0 && wc + 4 * m <= Wn - 4) vm1 |= 1 << m;
        }
    }
    const bool dual = tid < (NT - 256);  // 80 threads own a 2nd task
    if (dual) {
        int t2 = tid + 256;
        int r = t2 >> 3, g = t2 & 7;
        int hh = h0 - 5 + r, wc = w0 - 8 + 8 * g;
        xo2 = hh * Wn + wc; lo2 = r * WSS + 8 * g;
        if (hh >= 0 && hh < Hn) {
#pragma unroll
            for (int m = 0; m < 6; ++m)
                if (wc + 4 * m >= 0 && wc + 4 * m <= Wn - 4) vm2 |= 1 << m;
        }
    }

    // OOB task rows: zero both ws buffers once; never touched again
    {
        float4 z = {0.f, 0.f, 0.f, 0.f};
        if (!vm1) { *(float4*)&ws[0][lo1] = z; *(float4*)&ws[0][lo1 + 4] = z;
                    *(float4*)&ws[1][lo1] = z; *(float4*)&ws[1][lo1 + 4] = z; }
        if (dual && !vm2) { *(float4*)&ws[0][lo2] = z; *(float4*)&ws[0][lo2 + 4] = z;
                            *(float4*)&ws[1][lo2] = z; *(float4*)&ws[1][lo2 + 4] = z; }
    }

    // ---- pass 1: per-task rinv in registers ----
    float ri1[18], ri2[18];
    if (vm1) PASS1(xo1, vm1, ri1);
    if (dual && vm2) PASS1(xo2, vm2, ri2);

    // phase-B geometry: 2 rows x 4 cols per thread
    const int rs = tid >> 4, cg = tid & 15;
    const int bws = 2 * rs * WSS + 4 * cg;
    const int pix = (h0 + 2 * rs) * Wn + (w0 + 4 * cg);

    float4 xA = {0.f, 0.f, 0.f, 0.f}, xB = xA;   // x0 prefetch for channel c

#pragma unroll 1
    for (int c = 0; c < Cn; ++c) {
        // issue A(c) window loads (L1/L2-served; latency hides under B)
        float4 p1[6];
#pragma unroll
        for (int m = 0; m < 6; ++m) {
            float4 v = {0.f, 0.f, 0.f, 0.f};
            if ((vm1 >> m) & 1) v = *(const float4*)(xb + c * HWn + xo1 + 4 * m);
            p1[m] = v;
        }
        // B for previous channel
        if (c > 0) B_PHASE(c - 1, xA, xB);
        // prefetch x0 for channel c (consumed by B next iteration)
        {
            int gi = (b * Cn + c) * HWn + pix;
            xA = *(const float4*)(x0 + gi);
            xB = *(const float4*)(x0 + gi + Wn);
        }
        // A(c): softmax-on-the-fly + convW -> ws[c&1]
        if (vm1) A_STAGE(p1, ri1, vm1, lo1, (c & 1));
        if (dual && vm2) {
            float4 p2[6];
#pragma unroll
            for (int m = 0; m < 6; ++m) {
                float4 v = {0.f, 0.f, 0.f, 0.f};
                if ((vm2 >> m) & 1) v = *(const float4*)(xb + c * HWn + xo2 + 4 * m);
                p2[m] = v;
            }
            A_STAGE(p2, ri2, vm2, lo2, (c & 1));
        }
        __syncthreads();
    }
    B_PHASE(Cn - 1, xA, xB);
}

extern "C" void kernel_launch(void* const* d_in, const int* in_sizes, int n_in,
                              void* d_out, int out_size, void* d_ws, size_t ws_size,
                              hipStream_t stream) {
    const float* x0      = (const float*)d_in[0];
    const float* spacing = (const float*)d_in[1];
    const float* wgt     = (const float*)d_in[2];
    const float* itheta  = (const float*)d_in[3];
    float* out = (float*)d_out;

    float* A    = (float*)d_ws;          // ping-pong buffer (TOTn floats)
    float* taps = A + TOTn;

    k_taps<<<1, 256, 0, stream>>>(spacing, itheta, wgt, taps);

    // 1024 blocks, 1D; swizzle in-kernel (8x16x8 tiles)
    // double-buffered iterations: no kernel reads and writes the same tensor
    k_fused<<<1024, 256, 0, stream>>>(x0,  x0, out, taps);   // it0
    k_fused<<<1024, 256, 0, stream>>>(out, x0, A,   taps);   // it1
    k_fused<<<1024, 256, 0, stream>>>(A,   x0, out, taps);   // it2
    k_fused<<<1024, 256, 0, stream>>>(out, x0, A,   taps);   // it3
    k_fused<<<1024, 256, 0, stream>>>(A,   x0, out, taps);   // it4
}